// Round 13
// baseline (1425.356 us; speedup 1.0000x reference)
//
#include <hip/hip_runtime.h>
#include <hip/hip_bf16.h>

// Problem constants: B=64, T=512, I=1024, H=1024 (fp32 in/out).
#define BB_   64
#define TT_   512
#define II_   1024
#define HH_   1024

typedef _Float16 half8  __attribute__((ext_vector_type(8)));
typedef _Float16 half4v __attribute__((ext_vector_type(4)));
typedef float    f32x4  __attribute__((ext_vector_type(4)));

// tanh(x) = 1 - 2/(exp(2x)+1); clamp |x|<=16. ~6 ops vs ocml ~300cy.
__device__ __forceinline__ float fast_tanh(float x) {
    float t = fminf(fmaxf(x, -16.f), 16.f);
    float e = __builtin_amdgcn_exp2f(t * 2.885390082f);   // exp(2t)
    return 1.f - 2.f * __builtin_amdgcn_rcpf(e + 1.f);
}

// async global->LDS 16B copy (gfx950). LDS dest rule: wave-uniform base +
// lane*16 -- our per-lane dest is linear lane*16B within the wave window.
__device__ __forceinline__ void gload_lds16(const void* g, void* l) {
    __builtin_amdgcn_global_load_lds(
        (const __attribute__((address_space(1))) unsigned*)g,
        (__attribute__((address_space(3))) unsigned*)l, 16, 0, 0);
}

// ---------------------------------------------------------------------------
// f32 -> f16 convert pass (memory-bound). Same rounding as the old
// in-staging convert => bit-identical downstream math. (r10-proven)
// ---------------------------------------------------------------------------
__global__ __launch_bounds__(256) void cvt_f16(const float4* __restrict__ src,
                                               half4v* __restrict__ dst, int n4) {
    int i = blockIdx.x * blockDim.x + threadIdx.x;
    const int stride = gridDim.x * blockDim.x;
    for (; i < n4; i += stride) {
        const float4 v = src[i];
        half4v h = { (_Float16)v.x, (_Float16)v.y, (_Float16)v.z, (_Float16)v.w };
        dst[i] = h;
    }
}

// ---------------------------------------------------------------------------
// Phase 1 (fast path, r13): f16 GEMM, DOUBLE-BUFFERED global_load_lds.
// r12 exposed a full staging latency per K-iter (stage -> syncthreads
// vmcnt(0) drain -> compute). r13: BK=32 with As[2]/Bs[2] -- SAME 32KB LDS
// (occupancy unchanged ~4 blocks/CU, dodging the m132 64KB-LDS trap), SAME
// instruction counts as r12; only the schedule changes: tile k+1's loads
// issue BEFORE tile k's compute, so their latency hides under ds_read+MFMA
// and the end-of-iter barrier drains only the residual. One barrier/iter
// (buffer parity protects read/write disjointness).
// Swizzle (rule #21, both-sides): 4 chunks/row; lane fetches source chunk
// (l&3)^(row&3) into linear dest slot (l&3); reader takes slot q^(R&3).
// ---------------------------------------------------------------------------
__global__ __launch_bounds__(256) void gemm_xp_f16(const _Float16* __restrict__ xh,
                                                   const _Float16* __restrict__ Wh,
                                                   const float* __restrict__ bih,
                                                   float* __restrict__ out) {
    __shared__ alignas(16) _Float16 As[2][128 * 32];   // 2 x 8KB
    __shared__ alignas(16) _Float16 Bs[2][128 * 32];

    const int tid  = threadIdx.x;
    const int xcd  = blockIdx.x & 7;               // same-bm blocks share an XCD
    const int idx  = blockIdx.x >> 3;
    const int bm   = xcd + 8 * (idx >> 3);
    const int bn   = idx & 7;
    const int M0   = bm * 128, N0 = bn * 128;
    const int lane = tid & 63, w = tid >> 6;
    const int wm   = (w & 1) * 64, wn = (w >> 1) * 64;
    const int ro   = lane & 15, q = lane >> 4;

    // staging: pass ir in {0,1} stages rows ir*64 + w*16 + (lane>>2);
    // source chunk (l&3)^(row&3), dest = linear lane*16B (+4KB for ir=1).
    const int srow   = w * 16 + (lane >> 2);
    const int schunk = (lane & 3) ^ ((lane >> 2) & 3);
    const size_t soff = (size_t)srow * 32 + (size_t)(lane & 3) * 8; // == w*512+lane*8

    #define STAGE_(buf, kk_) do {                                              \
        const int k0_ = (kk_) * 32;                                            \
        gload_lds16(xh + (size_t)(M0 + srow) * II_ + k0_ + schunk * 8,         \
                    &As[buf][0] + soff);                                       \
        gload_lds16(xh + (size_t)(M0 + 64 + srow) * II_ + k0_ + schunk * 8,    \
                    &As[buf][0] + soff + 64 * 32);                             \
        gload_lds16(Wh + (size_t)(N0 + srow) * II_ + k0_ + schunk * 8,         \
                    &Bs[buf][0] + soff);                                       \
        gload_lds16(Wh + (size_t)(N0 + 64 + srow) * II_ + k0_ + schunk * 8,    \
                    &Bs[buf][0] + soff + 64 * 32);                             \
    } while (0)

    const f32x4 zero4 = {0.f, 0.f, 0.f, 0.f};
    f32x4 acc[4][4];
    #pragma unroll
    for (int i = 0; i < 4; ++i)
        #pragma unroll
        for (int j = 0; j < 4; ++j) acc[i][j] = zero4;

    STAGE_(0, 0);
    __syncthreads();           // drain prologue loads

    int cur = 0;
    for (int kk = 0; kk < 32; ++kk) {            // BK=32, 32 iters
        if (kk < 31) STAGE_(cur ^ 1, kk + 1);    // prefetch next tile FIRST

        half8 a[4], b[4];
        #pragma unroll
        for (int i = 0; i < 4; ++i) {
            const int Ra = wm + i * 16 + ro;     // Ra&3 == ro&3
            const int Rb = wn + i * 16 + ro;
            a[i] = *(const half8*)(&As[cur][0] + Ra * 32 + ((q ^ (Ra & 3)) * 8));
            b[i] = *(const half8*)(&Bs[cur][0] + Rb * 32 + ((q ^ (Rb & 3)) * 8));
        }
        #pragma unroll
        for (int i = 0; i < 4; ++i)
            #pragma unroll
            for (int j = 0; j < 4; ++j)
                acc[i][j] = __builtin_amdgcn_mfma_f32_16x16x32_f16(a[i], b[j], acc[i][j], 0, 0, 0);

        __syncthreads();       // joins WG + drains prefetch (overlapped above)
        cur ^= 1;
    }
    #undef STAGE_

    #pragma unroll
    for (int j = 0; j < 4; ++j) {
        const int col = N0 + wn + j * 16 + ro;
        const float bias = bih[col];
        #pragma unroll
        for (int i = 0; i < 4; ++i) {
            #pragma unroll
            for (int r = 0; r < 4; ++r) {
                const int rowg = M0 + wm + i * 16 + q * 4 + r;
                out[(size_t)rowg * HH_ + col] = acc[i][j][r] + bias;
            }
        }
    }
}

// ---------------------------------------------------------------------------
// Phase 1 (fallback, ws too small): r9 gemm verbatim.
// ---------------------------------------------------------------------------
__global__ __launch_bounds__(256) void gemm_xp(const float* __restrict__ x,
                                               const float* __restrict__ Wih,
                                               const float* __restrict__ bih,
                                               float* __restrict__ out) {
    __shared__ alignas(16) _Float16 As[2][128 * 40];
    __shared__ alignas(16) _Float16 Bs[2][128 * 40];

    const int tid  = threadIdx.x;
    const int xcd  = blockIdx.x & 7;
    const int idx  = blockIdx.x >> 3;
    const int bm   = xcd + 8 * (idx >> 3);
    const int bn   = idx & 7;
    const int M0   = bm * 128, N0 = bn * 128;
    const int lane = tid & 63, w = tid >> 6;
    const int wm   = (w & 1) * 64, wn = (w >> 1) * 64;
    const int ro   = lane & 15, q = lane >> 4;
    const int sr   = tid >> 3, sc = tid & 7;

    const f32x4 zero4 = {0.f, 0.f, 0.f, 0.f};
    f32x4 acc[4][4];
    #pragma unroll
    for (int i = 0; i < 4; ++i)
        #pragma unroll
        for (int j = 0; j < 4; ++j) acc[i][j] = zero4;

    for (int kk = 0; kk < 16; ++kk) {
        #pragma unroll
        for (int sub = 0; sub < 2; ++sub) {
            const int k0 = kk * 64 + sub * 32;
            #pragma unroll
            for (int ir = 0; ir < 4; ++ir) {
                const int row = ir * 32 + sr;
                const float4 av = *(const float4*)(x   + (size_t)(M0 + row) * II_ + k0 + sc * 4);
                const float4 bv = *(const float4*)(Wih + (size_t)(N0 + row) * II_ + k0 + sc * 4);
                half4v ah = { (_Float16)av.x, (_Float16)av.y, (_Float16)av.z, (_Float16)av.w };
                half4v bh = { (_Float16)bv.x, (_Float16)bv.y, (_Float16)bv.z, (_Float16)bv.w };
                *(half4v*)(As[sub] + row * 40 + sc * 4) = ah;
                *(half4v*)(Bs[sub] + row * 40 + sc * 4) = bh;
            }
        }
        __syncthreads();

        half8 a[2][4], b[2][4];
        #pragma unroll
        for (int sub = 0; sub < 2; ++sub)
            #pragma unroll
            for (int i = 0; i < 4; ++i) {
                a[sub][i] = *(const half8*)(As[sub] + (wm + i * 16 + ro) * 40 + q * 8);
                b[sub][i] = *(const half8*)(Bs[sub] + (wn + i * 16 + ro) * 40 + q * 8);
            }
        #pragma unroll
        for (int sub = 0; sub < 2; ++sub)
            #pragma unroll
            for (int i = 0; i < 4; ++i)
                #pragma unroll
                for (int j = 0; j < 4; ++j)
                    acc[i][j] = __builtin_amdgcn_mfma_f32_16x16x32_f16(a[sub][i], b[sub][j], acc[i][j], 0, 0, 0);
        __syncthreads();
    }

    #pragma unroll
    for (int j = 0; j < 4; ++j) {
        const int col = N0 + wn + j * 16 + ro;
        const float bias = bih[col];
        #pragma unroll
        for (int i = 0; i < 4; ++i) {
            #pragma unroll
            for (int r = 0; r < 4; ++r) {
                const int rowg = M0 + wm + i * 16 + q * 4 + r;
                out[(size_t)rowg * HH_ + col] = acc[i][j][r] + bias;
            }
        }
    }
}

// ---------------------------------------------------------------------------
// Phase 2: persistent recurrence -- r9/r11/r12 VERBATIM (best: ~1138us,
// four green runs). Simple single-round poll + 3-op XOR tag check. Retired
// by experiment: sc0 store (r2/r4 hang), sc0 poll (r3 +120us), fat-WG (r5),
// degree-8 (r7), fusion (r8), pipelined poll (r10).
// ---------------------------------------------------------------------------
__global__ __launch_bounds__(256, 1) void rnn_steps(const float* __restrict__ Whh,
                                                    const float* __restrict__ bhh,
                                                    const float* __restrict__ h0,
                                                    float* __restrict__ out,
                                                    unsigned* __restrict__ comm) {
    __shared__ alignas(16) _Float16 hbuf[2][5][1032];

    const int tid  = threadIdx.x;
    const int lane = tid & 63;
    const int w    = tid >> 6;             // wave id: stages batch w, owns 16 cols
    const int g    = blockIdx.x >> 4;      // group 0..15
    const int wg   = blockIdx.x & 15;      // wg within group
    const int b0   = g * 4;
    const int j0   = wg * 64;
    const int ro   = lane & 15, q = lane >> 4;
    const int arow = (ro < 4) ? ro : 4;    // A rows >=4 read the shared zero row
    const int bat  = lane >> 4;            // epilogue: this lane's batch 0..3
    const int colw = j0 + w * 16 + (lane & 15);  // epilogue: this lane's column

    half8 wf[4][8];
    {
        const float* wrow = Whh + (size_t)(j0 + w * 16 + ro) * HH_;
        #pragma unroll
        for (int kq = 0; kq < 4; ++kq) {
            #pragma unroll
            for (int ks = 0; ks < 8; ++ks) {
                const int kc = kq * 256 + ks * 32 + q * 8;
                const float4 w0 = *(const float4*)(wrow + kc);
                const float4 w1 = *(const float4*)(wrow + kc + 4);
                half8 hv;
                hv[0] = (_Float16)w0.x; hv[1] = (_Float16)w0.y;
                hv[2] = (_Float16)w0.z; hv[3] = (_Float16)w0.w;
                hv[4] = (_Float16)w1.x; hv[5] = (_Float16)w1.y;
                hv[6] = (_Float16)w1.z; hv[7] = (_Float16)w1.w;
                wf[kq][ks] = hv;
            }
        }
    }
    const float bhh_r = bhh[colw];

    for (int i = tid; i < 1032; i += 256) {
        hbuf[0][4][i] = (_Float16)0.f;
        hbuf[1][4][i] = (_Float16)0.f;
    }

    const f32x4 zero4 = {0.f, 0.f, 0.f, 0.f};

    #define TAGMSK_ 0xFFFF0000FFFF0000ull
    #define TAGOK_(v) ((((v) ^ pat) & TAGMSK_) == 0)

    for (int s = 0; s < TT_; ++s) {
        const int slot = s & 1;

        const float xpv = out[((size_t)(b0 + bat) * TT_ + s) * HH_ + colw];

        unsigned* dstw = (unsigned*)(&hbuf[slot][w][0]);
        if (s == 0) {
            const float2* hrow = (const float2*)(h0 + (size_t)(b0 + w) * HH_);
            #pragma unroll
            for (int c = 0; c < 8; ++c) {
                const float2 hv = hrow[c * 64 + lane];
                union { _Float16 h[2]; unsigned u; } pk;
                pk.h[0] = (_Float16)hv.x; pk.h[1] = (_Float16)hv.y;
                dstw[c * 64 + lane] = pk.u;
            }
        } else {
            const unsigned long long pat =
                ((unsigned long long)(unsigned)s << 48) |
                ((unsigned long long)(unsigned)s << 16);
            const unsigned long long* sp = (const unsigned long long*)
                (comm + (size_t)slot * (BB_ * HH_) + (size_t)(b0 + w) * HH_);
            unsigned long long v0, v1, v2, v3, v4, v5, v6, v7;
            bool ok = false;
            while (!ok) {
                v0 = __hip_atomic_load(sp + 0 * 64 + lane, __ATOMIC_RELAXED, __HIP_MEMORY_SCOPE_AGENT);
                v1 = __hip_atomic_load(sp + 1 * 64 + lane, __ATOMIC_RELAXED, __HIP_MEMORY_SCOPE_AGENT);
                v2 = __hip_atomic_load(sp + 2 * 64 + lane, __ATOMIC_RELAXED, __HIP_MEMORY_SCOPE_AGENT);
                v3 = __hip_atomic_load(sp + 3 * 64 + lane, __ATOMIC_RELAXED, __HIP_MEMORY_SCOPE_AGENT);
                v4 = __hip_atomic_load(sp + 4 * 64 + lane, __ATOMIC_RELAXED, __HIP_MEMORY_SCOPE_AGENT);
                v5 = __hip_atomic_load(sp + 5 * 64 + lane, __ATOMIC_RELAXED, __HIP_MEMORY_SCOPE_AGENT);
                v6 = __hip_atomic_load(sp + 6 * 64 + lane, __ATOMIC_RELAXED, __HIP_MEMORY_SCOPE_AGENT);
                v7 = __hip_atomic_load(sp + 7 * 64 + lane, __ATOMIC_RELAXED, __HIP_MEMORY_SCOPE_AGENT);
                bool o = true;
                o &= TAGOK_(v0); o &= TAGOK_(v1); o &= TAGOK_(v2); o &= TAGOK_(v3);
                o &= TAGOK_(v4); o &= TAGOK_(v5); o &= TAGOK_(v6); o &= TAGOK_(v7);
                ok = o;
            }
            #define PACK_(x) ((unsigned)((x) & 0xffffull) | (((unsigned)((x) >> 32)) << 16))
            dstw[0 * 64 + lane] = PACK_(v0);
            dstw[1 * 64 + lane] = PACK_(v1);
            dstw[2 * 64 + lane] = PACK_(v2);
            dstw[3 * 64 + lane] = PACK_(v3);
            dstw[4 * 64 + lane] = PACK_(v4);
            dstw[5 * 64 + lane] = PACK_(v5);
            dstw[6 * 64 + lane] = PACK_(v6);
            dstw[7 * 64 + lane] = PACK_(v7);
            #undef PACK_
        }
        __syncthreads();   // the only barrier per step (LDS double-buffered)

        f32x4 acc[4] = {zero4, zero4, zero4, zero4};
        const _Float16* abase = &hbuf[slot][0][0] + (size_t)arow * 1032;
        #pragma unroll
        for (int kq = 0; kq < 4; ++kq) {
            #pragma unroll
            for (int ks = 0; ks < 8; ++ks) {
                const half8 a = *(const half8*)(abase + kq * 256 + ks * 32 + q * 8);
                acc[kq] = __builtin_amdgcn_mfma_f32_16x16x32_f16(a, wf[kq][ks], acc[kq], 0, 0, 0);
            }
        }

        const f32x4 sum = acc[0] + acc[1] + acc[2] + acc[3];
        const float t0 = __shfl(sum[0], lane & 15);
        const float t1 = __shfl(sum[1], lane & 15);
        const float t2 = __shfl(sum[2], lane & 15);
        const float t3 = __shfl(sum[3], lane & 15);
        const float val = (bat == 0) ? t0 : (bat == 1) ? t1 : (bat == 2) ? t2 : t3;

        const float hnew = fast_tanh(xpv + bhh_r + val);

        union { _Float16 h; unsigned short us; } cv; cv.h = (_Float16)hnew;
        const unsigned word = ((unsigned)(s + 1) << 16) | (unsigned)cv.us;
        __hip_atomic_store(comm + (size_t)((s + 1) & 1) * (BB_ * HH_)
                                + (size_t)(b0 + bat) * HH_ + colw,
                           word, __ATOMIC_RELAXED, __HIP_MEMORY_SCOPE_AGENT);

        out[((size_t)(b0 + bat) * TT_ + s) * HH_ + colw] = hnew;
    }
    #undef TAGOK_
    #undef TAGMSK_
}

// ---------------------------------------------------------------------------
extern "C" void kernel_launch(void* const* d_in, const int* in_sizes, int n_in,
                              void* d_out, int out_size, void* d_ws, size_t ws_size,
                              hipStream_t stream) {
    (void)in_sizes; (void)n_in; (void)out_size;

    const float* x   = (const float*)d_in[0];
    const float* h0  = (const float*)d_in[1];
    const float* Wih = (const float*)d_in[2];
    const float* bih = (const float*)d_in[3];
    const float* Whh = (const float*)d_in[4];
    const float* bhh = (const float*)d_in[5];
    float* out = (float*)d_out;

    // ws layout: comm (512KB, r1-proven offsets) | Wih_f16 (2MB) | x_f16 (64MB)
    const size_t COMMB = 2 * (size_t)(BB_ * HH_) * sizeof(unsigned);
    const size_t WFB   = (size_t)HH_ * II_ * sizeof(_Float16);
    const size_t XFB   = (size_t)BB_ * TT_ * II_ * sizeof(_Float16);
    unsigned* comm = (unsigned*)d_ws;

    if (ws_size >= COMMB + WFB + XFB) {
        _Float16* Wh = (_Float16*)((char*)d_ws + COMMB);
        _Float16* xh = (_Float16*)((char*)d_ws + COMMB + WFB);
        cvt_f16<<<512, 256, 0, stream>>>((const float4*)Wih, (half4v*)Wh,
                                         HH_ * II_ / 4);
        cvt_f16<<<2048, 256, 0, stream>>>((const float4*)x, (half4v*)xh,
                                          BB_ * TT_ * II_ / 4);
        gemm_xp_f16<<<2048, 256, 0, stream>>>(xh, Wh, bih, out);
    } else {
        gemm_xp<<<2048, 256, 0, stream>>>(x, Wih, bih, out);
    }
    rnn_steps<<<256, 256, 0, stream>>>(Whh, bhh, h0, out, comm);
}